// Round 5
// baseline (206.534 us; speedup 1.0000x reference)
//
#include <hip/hip_runtime.h>
#include <hip/hip_bf16.h>

#define NJ 24
#define NV 6890
#define NR (NV*3)        // 20670 output rows per batch
#define NPF 207
#define KB 217           // 207 pf + 10 beta
#define KP 256           // padded K (8 x 32)
#define NT 162           // n-tiles (162*128 = 20736 >= NR)
#define NRP (NT*128)
#define NSPLIT 512       // jdirs v-splits
#define VPB 14           // ceil(6890/512)

typedef short s16x8 __attribute__((ext_vector_type(8)));
typedef float f32x4 __attribute__((ext_vector_type(4)));
typedef float f4u   __attribute__((ext_vector_type(4), aligned(4)));

__device__ constexpr int PAR[24] = {-1,0,0,0,1,2,3,4,5,6,7,8,9,9,9,12,13,14,16,17,18,19,20,21};

__device__ __forceinline__ short f2bf(float f) {
    __hip_bfloat16 h = __float2bfloat16(f);
    return *reinterpret_cast<short*>(&h);
}

// ============ K1: Rodrigues -> Rws(f32), pfA(f32 plain), Atiles(bf16 swizzled) ============
__global__ __launch_bounds__(256) void k_rodrigues(const float* __restrict__ theta,
        const float* __restrict__ beta, float* __restrict__ Rws,
        float* __restrict__ pfA, short* __restrict__ Atiles, int B) {
    int idx = blockIdx.x * blockDim.x + threadIdx.x;   // b*24 + j
    if (idx >= B * NJ) return;
    int b = idx / NJ, j = idx % NJ;
    float x = theta[b*72 + j*3 + 0];
    float y = theta[b*72 + j*3 + 1];
    float z = theta[b*72 + j*3 + 2];
    float n = sqrtf(x*x + y*y + z*z);
    float a = fmaxf(n, 1e-8f);
    float inv = 1.0f / a;
    float ix = x*inv, iy = y*inv, iz = z*inv;
    float c = cosf(a), s = sinf(a), t = 1.0f - c;
    float r[9];
    r[0] = t*ix*ix + c;     r[1] = t*ix*iy - s*iz;  r[2] = t*ix*iz + s*iy;
    r[3] = t*ix*iy + s*iz;  r[4] = t*iy*iy + c;     r[5] = t*iy*iz - s*ix;
    r[6] = t*ix*iz - s*iy;  r[7] = t*iy*iz + s*ix;  r[8] = t*iz*iz + c;
    float* Rp = Rws + (size_t)idx * 9;
    #pragma unroll
    for (int k = 0; k < 9; ++k) Rp[k] = r[k];

    int rb = b & 127;
    int hs = (rb >> 1) & 7;
    short* At = Atiles + (size_t)(b >> 7) * (128*KP) + (size_t)rb * KP;
    float* pa = pfA + (size_t)b * 224;
    if (j >= 1) {
        #pragma unroll
        for (int kk = 0; kk < 9; ++kk) {
            int k = (j-1)*9 + kk;
            float f = r[kk] - ((kk == 0 || kk == 4 || kk == 8) ? 1.0f : 0.0f);
            At[(((k>>3) ^ hs) << 3) + (k & 7)] = f2bf(f);
            pa[k] = f;
        }
    } else {
        #pragma unroll
        for (int kk = 0; kk < 10; ++kk) {
            int k = NPF + kk;
            float f = beta[b*10 + kk];
            At[(((k>>3) ^ hs) << 3) + (k & 7)] = f2bf(f);
            pa[k] = f;
        }
        for (int k = KB; k < KP; ++k)
            At[(((k>>3) ^ hs) << 3) + (k & 7)] = 0;
    }
}

// ============ K2: build Btiles (bf16, tile-contiguous, chunk-swizzled) ============
__global__ __launch_bounds__(256) void k_convB(const float* __restrict__ pd,
        const float* __restrict__ sd, short* __restrict__ Btiles) {
    int idx = blockIdx.x * 256 + threadIdx.x;          // (rg, chunk)
    int rg = idx >> 5, c = idx & 31;
    int r = rg & 127, nt = rg >> 7;
    s16x8 v;
    if (rg < NR) {
        int k0 = c * 8;
        if (k0 + 7 < NPF) {
            const float* p = pd + (size_t)rg * NPF + k0;
            #pragma unroll
            for (int k = 0; k < 8; ++k) v[k] = f2bf(p[k]);
        } else {
            #pragma unroll
            for (int k = 0; k < 8; ++k) {
                int col = k0 + k;
                float f = 0.0f;
                if (col < NPF)     f = pd[(size_t)rg * NPF + col];
                else if (col < KB) f = sd[(size_t)rg * 10 + (col - NPF)];
                v[k] = f2bf(f);
            }
        }
    } else {
        #pragma unroll
        for (int k = 0; k < 8; ++k) v[k] = 0;
    }
    int csw = c ^ ((r >> 1) & 7);
    *(s16x8*)&Btiles[(size_t)nt * (128*KP) + (size_t)r * KP + csw * 8] = v;
}

// ============ K3: JD partials (512 splits, Jreg chunk in LDS) ============
__global__ __launch_bounds__(256) void k_jdirs(const float* __restrict__ pd,
        const float* __restrict__ sd, const float* __restrict__ vt,
        const float* __restrict__ Jreg, float* __restrict__ part) {
    __shared__ float wjs[24][VPB];
    int bi = blockIdx.x;
    int v0 = bi * VPB;
    int nv = NV - v0; if (nv > VPB) nv = VPB; if (nv < 0) nv = 0;
    for (int i = threadIdx.x; i < 24*VPB; i += 256) {
        int j = i / VPB, vv = i - j*VPB;
        wjs[j][vv] = (vv < nv) ? Jreg[(size_t)j * NV + v0 + vv] : 0.0f;
    }
    __syncthreads();
    int k = threadIdx.x;
    float acc[72];
    #pragma unroll
    for (int i = 0; i < 72; ++i) acc[i] = 0.0f;
    for (int vv = 0; vv < VPB; ++vv) {
        int v = v0 + vv;
        if (v >= NV) break;
        #pragma unroll
        for (int c = 0; c < 3; ++c) {
            int row = v*3 + c;
            float val = 0.0f;
            if (k < NPF)      val = pd[(size_t)row * NPF + k];
            else if (k < KB)  val = sd[(size_t)row * 10 + (k - NPF)];
            else if (k == KB) val = vt[row];
            #pragma unroll
            for (int j = 0; j < 24; ++j) acc[j*3 + c] += wjs[j][vv] * val;
        }
    }
    if (k <= KB) {
        float* p = part + ((size_t)bi * 224 + k) * 72;
        #pragma unroll
        for (int i = 0; i < 72; ++i) p[i] = acc[i];
    }
}

// ============ K4: reduce partials -> JDt[k][72] (4 threads per elem) ============
__global__ __launch_bounds__(256) void k_jreduce(const float* __restrict__ part,
        float* __restrict__ JDt) {
    __shared__ float red[256];
    int e = blockIdx.x * 64 + (threadIdx.x >> 2);
    int p4 = threadIdx.x & 3;
    float s = 0.0f;
    if (e < 218*72) {
        for (int bi = p4; bi < NSPLIT; bi += 4)
            s += part[(size_t)bi * (224*72) + e];
    }
    red[threadIdx.x] = s;
    __syncthreads();
    if (p4 == 0 && e < 218*72)
        JDt[e] = red[threadIdx.x] + red[threadIdx.x+1] + red[threadIdx.x+2] + red[threadIdx.x+3];
}

// ============ K5: J[b][jc] = JDt[217][jc] + sum_k pfA[b][k]*JDt[k][jc] ============
__global__ __launch_bounds__(128) void k_J(const float* __restrict__ pfA,
        const float* __restrict__ JDt, float* __restrict__ Jout, int B) {
    int b = blockIdx.x, t = threadIdx.x;
    if (t >= 72) return;
    const float* pa = pfA + (size_t)b * 224;
    float acc = JDt[217*72 + t];
    #pragma unroll 7
    for (int k = 0; k < KB; ++k) acc += pa[k] * JDt[k*72 + t];
    Jout[(size_t)b * 72 + t] = acc;
}

// ============ K6: MFMA GEMM, 4-chunk double-buffered pipeline + LDS epilogue ============
// LDS: 2 bufs x (A 8192 + B 8192) shorts = 64 KB; epilogue reuses as float[128][128] swizzled.
__global__ __launch_bounds__(256) void k_gemm(const short* __restrict__ At,
        const short* __restrict__ Bt, const float* __restrict__ vt,
        float* __restrict__ vout, int B) {
    extern __shared__ short lds[];
    const int t = threadIdx.x;
    const int nt = blockIdx.x, bt = blockIdx.y;
    const int wave = t >> 6, lane = t & 63;
    const short* Asrc = At + (size_t)bt * (128*KP);
    const short* Bsrc = Bt + (size_t)nt * (128*KP);

    const int wm = (wave >> 1) * 64, wn = (wave & 1) * 64;
    const int q = lane >> 4, r16 = lane & 15;
    const int hs = (r16 >> 1) & 7;

    // per-chunk staging: 8 gload_lds/thread (4 A + 4 B), each wave-instr = 8 rows x 64 shorts
#define STAGE(h, s)                                                                        \
    {                                                                                      \
        short* base_ = lds + (s) * 16384;                                                  \
        _Pragma("unroll")                                                                  \
        for (int it = 0; it < 4; ++it) {                                                   \
            int r0 = (it * 4 + wave) * 8;                                                  \
            __builtin_amdgcn_global_load_lds(                                              \
                Asrc + (size_t)(r0 + (lane >> 3)) * KP + (h) * 64 + (lane & 7) * 8,        \
                base_ + r0 * 64, 16, 0, 0);                                                \
        }                                                                                  \
        _Pragma("unroll")                                                                  \
        for (int it = 0; it < 4; ++it) {                                                   \
            int r0 = (it * 4 + wave) * 8;                                                  \
            __builtin_amdgcn_global_load_lds(                                              \
                Bsrc + (size_t)(r0 + (lane >> 3)) * KP + (h) * 64 + (lane & 7) * 8,        \
                base_ + 8192 + r0 * 64, 16, 0, 0);                                         \
        }                                                                                  \
    }

    f32x4 acc[4][4];
    #pragma unroll
    for (int m = 0; m < 4; ++m)
        #pragma unroll
        for (int n = 0; n < 4; ++n)
            #pragma unroll
            for (int i = 0; i < 4; ++i) acc[m][n][i] = 0.0f;

    STAGE(0, 0);
    #pragma unroll
    for (int h = 0; h < 4; ++h) {
        const int cur = h & 1;
        if (h < 3) {
            STAGE(h + 1, cur ^ 1);
            asm volatile("s_waitcnt vmcnt(8)" ::: "memory");   // chunk h landed, h+1 in flight
        } else {
            asm volatile("s_waitcnt vmcnt(0)" ::: "memory");
        }
        __builtin_amdgcn_s_barrier();
        __builtin_amdgcn_sched_barrier(0);
        const short* bA = lds + cur * 16384;
        const short* bB = bA + 8192;
        #pragma unroll
        for (int ksl = 0; ksl < 2; ++ksl) {
            const int csw = ((ksl*4 + q) ^ hs) * 8;
            s16x8 af[4], bf[4];
            #pragma unroll
            for (int m = 0; m < 4; ++m)
                af[m] = *(const s16x8*)(bA + (wm + m*16 + r16) * 64 + csw);
            #pragma unroll
            for (int n = 0; n < 4; ++n)
                bf[n] = *(const s16x8*)(bB + (wn + n*16 + r16) * 64 + csw);
            #pragma unroll
            for (int m = 0; m < 4; ++m)
                #pragma unroll
                for (int n = 0; n < 4; ++n)
                    acc[m][n] = __builtin_amdgcn_mfma_f32_16x16x32_bf16(af[m], bf[n], acc[m][n], 0, 0, 0);
        }
        __builtin_amdgcn_s_barrier();
        __builtin_amdgcn_sched_barrier(0);
    }
#undef STAGE

    // ---- epilogue: transpose through LDS (XOR-swizzled, conflict-free), full-line writes ----
    float* eld = (float*)lds;
    #pragma unroll
    for (int m = 0; m < 4; ++m) {
        #pragma unroll
        for (int n = 0; n < 4; ++n) {
            #pragma unroll
            for (int i = 0; i < 4; ++i) {
                int row = wm + m*16 + q*4 + i;
                int col = wn + n*16 + r16;
                eld[row * 128 + (col ^ ((row & 7) << 2))] = acc[m][n][i];
            }
        }
    }
    __syncthreads();
    {
        int row = t >> 1, ch = (t & 1) * 64;
        int bg = bt*128 + row;
        int rbase = nt*128 + ch;
        if (bg < B) {
            float* dst = vout + (size_t)bg * NR + rbase;
            #pragma unroll
            for (int i = 0; i < 16; ++i) {
                int col = ch + i*4;
                int rg = rbase + i*4;
                const float* src = &eld[row * 128 + (col ^ ((row & 7) << 2))];
                if (rg + 3 < NR) {
                    f4u vv = *(const f4u*)src;
                    float4 tv = *(const float4*)(vt + rg);
                    vv[0] += tv.x; vv[1] += tv.y; vv[2] += tv.z; vv[3] += tv.w;
                    *(f4u*)(dst + i*4) = vv;
                } else {
                    for (int e = 0; e < 4; ++e)
                        if (rg + e < NR) dst[i*4 + e] = src[e] + vt[rg + e];
                }
            }
        }
    }
}

// ============ K7: kinematic chain -> G_corr (B,24,12) ============
__global__ __launch_bounds__(32) void k_chain(const float* __restrict__ Rg,
        const float* __restrict__ Jg, float* __restrict__ Gc, int B) {
    __shared__ float Gs[32 * 289];
    int b = blockIdx.x * 32 + threadIdx.x;
    if (b >= B) return;
    float* G = &Gs[threadIdx.x * 289];
    float Jl[72];
    const float* Jb = Jg + (size_t)b * 72;
    #pragma unroll
    for (int i = 0; i < 72; ++i) Jl[i] = Jb[i];
    const float* Rb = Rg + (size_t)b * 216;
    G[0]=Rb[0]; G[1]=Rb[1]; G[2]=Rb[2];  G[3]=Jl[0];
    G[4]=Rb[3]; G[5]=Rb[4]; G[6]=Rb[5];  G[7]=Jl[1];
    G[8]=Rb[6]; G[9]=Rb[7]; G[10]=Rb[8]; G[11]=Jl[2];
    #pragma unroll
    for (int i = 1; i < NJ; ++i) {
        const int p = PAR[i];
        const float* Ri = Rb + i*9;
        float r00=Ri[0],r01=Ri[1],r02=Ri[2];
        float r10=Ri[3],r11=Ri[4],r12=Ri[5];
        float r20=Ri[6],r21=Ri[7],r22=Ri[8];
        float px=Jl[p*3+0], py=Jl[p*3+1], pz=Jl[p*3+2];
        float tx = Jl[i*3+0] - (r00*px + r01*py + r02*pz);
        float ty = Jl[i*3+1] - (r10*px + r11*py + r12*pz);
        float tz = Jl[i*3+2] - (r20*px + r21*py + r22*pz);
        const float* gp = &G[p*12];
        float* gi = &G[i*12];
        #pragma unroll
        for (int rr = 0; rr < 3; ++rr) {
            float a0=gp[rr*4+0], a1=gp[rr*4+1], a2=gp[rr*4+2], a3=gp[rr*4+3];
            gi[rr*4+0] = a0*r00 + a1*r10 + a2*r20;
            gi[rr*4+1] = a0*r01 + a1*r11 + a2*r21;
            gi[rr*4+2] = a0*r02 + a1*r12 + a2*r22;
            gi[rr*4+3] = a0*tx + a1*ty + a2*tz + a3;
        }
    }
    float* out = Gc + (size_t)b * 288;
    #pragma unroll
    for (int i = 0; i < NJ; ++i) {
        const float* gi = &G[i*12];
        float jx=Jl[i*3+0], jy=Jl[i*3+1], jz=Jl[i*3+2];
        #pragma unroll
        for (int rr = 0; rr < 3; ++rr) {
            out[i*12+rr*4+0] = gi[rr*4+0];
            out[i*12+rr*4+1] = gi[rr*4+1];
            out[i*12+rr*4+2] = gi[rr*4+2];
            out[i*12+rr*4+3] = gi[rr*4+3] - (gi[rr*4+0]*jx + gi[rr*4+1]*jy + gi[rr*4+2]*jz);
        }
    }
}

// ============ K8: MFMA skinning ============
__global__ __launch_bounds__(256) void k_skin(float* __restrict__ vio,
        const float* __restrict__ W, const float* __restrict__ Gc, int B) {
    __shared__ short Gm[16 * 40];      // [comp][joint], stride 40, zero-padded
    const int t = threadIdx.x;
    const int wave = t >> 6, lane = t & 63;
    const int q = lane >> 4, c = lane & 15;
    const int vb = blockIdx.x * 256 + wave * 64;
    const int b0 = blockIdx.y * 8;

    if (t < 320) ((int*)Gm)[t] = 0;

    s16x8 wf[4];
    #pragma unroll
    for (int m = 0; m < 4; ++m) {
        int vert = vb + m*16 + c;
        if (q < 3 && vert < NV) {
            const float* wp = W + (size_t)vert * NJ + q*8;
            float4 f0 = *(const float4*)(wp);
            float4 f1 = *(const float4*)(wp + 4);
            wf[m][0]=f2bf(f0.x); wf[m][1]=f2bf(f0.y); wf[m][2]=f2bf(f0.z); wf[m][3]=f2bf(f0.w);
            wf[m][4]=f2bf(f1.x); wf[m][5]=f2bf(f1.y); wf[m][6]=f2bf(f1.z); wf[m][7]=f2bf(f1.w);
        } else {
            #pragma unroll
            for (int e = 0; e < 8; ++e) wf[m][e] = 0;
        }
    }
    __syncthreads();

    for (int bb = 0; bb < 8; ++bb) {
        int b = b0 + bb;
        {
            int i0 = t;
            int j0 = i0 / 12, c0 = i0 - j0*12;
            if (i0 < 288) Gm[c0*40 + j0] = f2bf(Gc[(size_t)b*288 + i0]);
            int i1 = t + 256;
            if (i1 < 288) {
                int j1 = i1 / 12, c1 = i1 - j1*12;
                Gm[c1*40 + j1] = f2bf(Gc[(size_t)b*288 + i1]);
            }
        }
        __syncthreads();

        s16x8 af = *(const s16x8*)&Gm[c*40 + q*8];
        #pragma unroll
        for (int m = 0; m < 4; ++m) {
            f32x4 zz = {0.0f, 0.0f, 0.0f, 0.0f};
            f32x4 acc = __builtin_amdgcn_mfma_f32_16x16x32_bf16(af, wf[m], zz, 0, 0, 0);
            int vert = vb + m*16 + c;
            bool ok = (q < 3) && (vert < NV);
            if (ok) {
                float* vp = vio + (size_t)b * NR + (size_t)vert * 3;
                float x = vp[0], y = vp[1], z = vp[2];
                float o = acc[0]*x + acc[1]*y + acc[2]*z + acc[3];
                vp[q] = o;
            }
        }
        __syncthreads();
    }
}

extern "C" void kernel_launch(void* const* d_in, const int* in_sizes, int n_in,
                              void* d_out, int out_size, void* d_ws, size_t ws_size,
                              hipStream_t stream) {
    const float* theta = (const float*)d_in[0];
    const float* beta  = (const float*)d_in[1];
    const float* sd    = (const float*)d_in[2];
    const float* pd    = (const float*)d_in[3];
    const float* Jreg  = (const float*)d_in[4];
    const float* vt    = (const float*)d_in[5];
    const float* W     = (const float*)d_in[6];
    float* out = (float*)d_out;

    const int B = in_sizes[0] / 72;

    float* vregion = out;
    float* Jout    = out + (size_t)B * NR;

    float* Rws   = (float*)d_ws;                          // B*216 f32
    float* Gcws  = Rws + (size_t)B * 216;                 // B*288 f32
    float* pfA   = Gcws + (size_t)B * 288;                // B*224 f32
    short* Atile = (short*)(pfA + (size_t)B * 224);       // (B/128)*128*256 bf16
    short* Btile = Atile + (size_t)(B/128) * 128 * KP;    // 162*128*256 bf16

    float* part = vregion;                                // d_out scratch pre-GEMM (33 MB < 84 MB)
    float* JDt  = vregion + (size_t)NSPLIT * 224 * 72;

    k_rodrigues<<<(B*NJ + 255)/256, 256, 0, stream>>>(theta, beta, Rws, pfA, Atile, B);
    k_convB<<<(NRP*32)/256, 256, 0, stream>>>(pd, sd, Btile);
    k_jdirs<<<NSPLIT, 256, 0, stream>>>(pd, sd, vt, Jreg, part);
    k_jreduce<<<(218*72 + 63)/64, 256, 0, stream>>>(part, JDt);
    k_J<<<B, 128, 0, stream>>>(pfA, JDt, Jout, B);
    k_chain<<<(B + 31)/32, 32, 0, stream>>>(Rws, Jout, Gcws, B);
    {
        dim3 grid(NT, B/128);
        k_gemm<<<grid, 256, 65536, stream>>>(Atile, Btile, vt, vregion, B);
    }
    {
        dim3 grid((NV + 255)/256, (B + 7)/8);
        k_skin<<<grid, 256, 0, stream>>>(vregion, W, Gcws, B);
    }
}

// Round 6
// 195.904 us; speedup vs baseline: 1.0543x; 1.0543x over previous
//
#include <hip/hip_runtime.h>
#include <hip/hip_bf16.h>

#define NJ 24
#define NV 6890
#define NR (NV*3)        // 20670 output rows per batch
#define NPF 207
#define KB 217           // 207 pf + 10 beta
#define KP 256           // padded K (8 x 32)
#define NT 162           // n-tiles (162*128 = 20736 >= NR)
#define NRP (NT*128)
#define NSPLIT 512       // jdirs v-splits
#define VPB 14           // ceil(6890/512)

typedef short s16x8 __attribute__((ext_vector_type(8)));
typedef float f32x4 __attribute__((ext_vector_type(4)));
typedef float f4u   __attribute__((ext_vector_type(4), aligned(4)));

__device__ constexpr int PAR[24] = {-1,0,0,0,1,2,3,4,5,6,7,8,9,9,9,12,13,14,16,17,18,19,20,21};

__device__ __forceinline__ short f2bf(float f) {
    __hip_bfloat16 h = __float2bfloat16(f);
    return *reinterpret_cast<short*>(&h);
}

// ============ K1: Rodrigues -> Rws(f32), pfA(f32 plain), Atiles(bf16 swizzled) ============
__global__ __launch_bounds__(256) void k_rodrigues(const float* __restrict__ theta,
        const float* __restrict__ beta, float* __restrict__ Rws,
        float* __restrict__ pfA, short* __restrict__ Atiles, int B) {
    int idx = blockIdx.x * blockDim.x + threadIdx.x;   // b*24 + j
    if (idx >= B * NJ) return;
    int b = idx / NJ, j = idx % NJ;
    float x = theta[b*72 + j*3 + 0];
    float y = theta[b*72 + j*3 + 1];
    float z = theta[b*72 + j*3 + 2];
    float n = sqrtf(x*x + y*y + z*z);
    float a = fmaxf(n, 1e-8f);
    float inv = 1.0f / a;
    float ix = x*inv, iy = y*inv, iz = z*inv;
    float c = cosf(a), s = sinf(a), t = 1.0f - c;
    float r[9];
    r[0] = t*ix*ix + c;     r[1] = t*ix*iy - s*iz;  r[2] = t*ix*iz + s*iy;
    r[3] = t*ix*iy + s*iz;  r[4] = t*iy*iy + c;     r[5] = t*iy*iz - s*ix;
    r[6] = t*ix*iz - s*iy;  r[7] = t*iy*iz + s*ix;  r[8] = t*iz*iz + c;
    float* Rp = Rws + (size_t)idx * 9;
    #pragma unroll
    for (int k = 0; k < 9; ++k) Rp[k] = r[k];

    int rb = b & 127;
    int hs = (rb >> 1) & 7;
    short* At = Atiles + (size_t)(b >> 7) * (128*KP) + (size_t)rb * KP;
    float* pa = pfA + (size_t)b * 224;
    if (j >= 1) {
        #pragma unroll
        for (int kk = 0; kk < 9; ++kk) {
            int k = (j-1)*9 + kk;
            float f = r[kk] - ((kk == 0 || kk == 4 || kk == 8) ? 1.0f : 0.0f);
            At[(((k>>3) ^ hs) << 3) + (k & 7)] = f2bf(f);
            pa[k] = f;
        }
    } else {
        #pragma unroll
        for (int kk = 0; kk < 10; ++kk) {
            int k = NPF + kk;
            float f = beta[b*10 + kk];
            At[(((k>>3) ^ hs) << 3) + (k & 7)] = f2bf(f);
            pa[k] = f;
        }
        for (int k = KB; k < KP; ++k)
            At[(((k>>3) ^ hs) << 3) + (k & 7)] = 0;
    }
}

// ============ K2: build Btiles (bf16, tile-contiguous, chunk-swizzled) ============
__global__ __launch_bounds__(256) void k_convB(const float* __restrict__ pd,
        const float* __restrict__ sd, short* __restrict__ Btiles) {
    int idx = blockIdx.x * 256 + threadIdx.x;          // (rg, chunk)
    int rg = idx >> 5, c = idx & 31;
    int r = rg & 127, nt = rg >> 7;
    s16x8 v;
    if (rg < NR) {
        int k0 = c * 8;
        if (k0 + 7 < NPF) {
            const float* p = pd + (size_t)rg * NPF + k0;
            #pragma unroll
            for (int k = 0; k < 8; ++k) v[k] = f2bf(p[k]);
        } else {
            #pragma unroll
            for (int k = 0; k < 8; ++k) {
                int col = k0 + k;
                float f = 0.0f;
                if (col < NPF)     f = pd[(size_t)rg * NPF + col];
                else if (col < KB) f = sd[(size_t)rg * 10 + (col - NPF)];
                v[k] = f2bf(f);
            }
        }
    } else {
        #pragma unroll
        for (int k = 0; k < 8; ++k) v[k] = 0;
    }
    int csw = c ^ ((r >> 1) & 7);
    *(s16x8*)&Btiles[(size_t)nt * (128*KP) + (size_t)r * KP + csw * 8] = v;
}

// ============ K3: JD partials, part layout [bi][i(72)][k(224)] for contiguous stores ============
__global__ __launch_bounds__(256) void k_jdirs(const float* __restrict__ pd,
        const float* __restrict__ sd, const float* __restrict__ vt,
        const float* __restrict__ Jreg, float* __restrict__ part) {
    __shared__ float wjs[24][VPB];
    int bi = blockIdx.x;
    int v0 = bi * VPB;
    int nv = NV - v0; if (nv > VPB) nv = VPB; if (nv < 0) nv = 0;
    for (int i = threadIdx.x; i < 24*VPB; i += 256) {
        int j = i / VPB, vv = i - j*VPB;
        wjs[j][vv] = (vv < nv) ? Jreg[(size_t)j * NV + v0 + vv] : 0.0f;
    }
    __syncthreads();
    int k = threadIdx.x;
    float acc[72];
    #pragma unroll
    for (int i = 0; i < 72; ++i) acc[i] = 0.0f;
    for (int vv = 0; vv < VPB; ++vv) {
        int v = v0 + vv;
        if (v >= NV) break;
        #pragma unroll
        for (int c = 0; c < 3; ++c) {
            int row = v*3 + c;
            float val = 0.0f;
            if (k < NPF)      val = pd[(size_t)row * NPF + k];
            else if (k < KB)  val = sd[(size_t)row * 10 + (k - NPF)];
            else if (k == KB) val = vt[row];
            #pragma unroll
            for (int j = 0; j < 24; ++j) acc[j*3 + c] += wjs[j][vv] * val;
        }
    }
    if (k < 224) {                      // lanes 218..223 write zeros -> full 896B lines
        float* p = part + (size_t)bi * (72*224);
        #pragma unroll
        for (int i = 0; i < 72; ++i) p[i*224 + k] = acc[i];
    }
}

// ============ K4: reduce partials -> JDt[k][72] ============
__global__ __launch_bounds__(256) void k_jreduce(const float* __restrict__ part,
        float* __restrict__ JDt) {
    __shared__ float red[256];
    int e = blockIdx.x * 64 + (threadIdx.x >> 2);      // e = k*72 + i
    int p4 = threadIdx.x & 3;
    float s = 0.0f;
    int k = e / 72, i = e - k * 72;
    if (e < 218*72) {
        for (int bi = p4; bi < NSPLIT; bi += 4)
            s += part[(size_t)bi * (72*224) + i*224 + k];
    }
    red[threadIdx.x] = s;
    __syncthreads();
    if (p4 == 0 && e < 218*72)
        JDt[e] = red[threadIdx.x] + red[threadIdx.x+1] + red[threadIdx.x+2] + red[threadIdx.x+3];
}

// ============ K5: J[b][jc] = JDt[217][jc] + sum_k pfA[b][k]*JDt[k][jc] ============
__global__ __launch_bounds__(128) void k_J(const float* __restrict__ pfA,
        const float* __restrict__ JDt, float* __restrict__ Jout, int B) {
    int b = blockIdx.x, t = threadIdx.x;
    if (t >= 72) return;
    const float* pa = pfA + (size_t)b * 224;
    float acc = JDt[217*72 + t];
    #pragma unroll 7
    for (int k = 0; k < KB; ++k) acc += pa[k] * JDt[k*72 + t];
    Jout[(size_t)b * 72 + t] = acc;
}

// ============ K6: MFMA GEMM, pipelined, epilogue with 512B-contiguous wave stores ============
__global__ __launch_bounds__(256) void k_gemm(const short* __restrict__ At,
        const short* __restrict__ Bt, const float* __restrict__ vt,
        float* __restrict__ vout, int B) {
    extern __shared__ short lds[];
    const int t = threadIdx.x;
    const int nt = blockIdx.x, bt = blockIdx.y;
    const int wave = t >> 6, lane = t & 63;
    const short* Asrc = At + (size_t)bt * (128*KP);
    const short* Bsrc = Bt + (size_t)nt * (128*KP);

    const int wm = (wave >> 1) * 64, wn = (wave & 1) * 64;
    const int q = lane >> 4, r16 = lane & 15;
    const int hs = (r16 >> 1) & 7;

#define STAGE(h, s)                                                                        \
    {                                                                                      \
        short* base_ = lds + (s) * 16384;                                                  \
        _Pragma("unroll")                                                                  \
        for (int it = 0; it < 4; ++it) {                                                   \
            int r0 = (it * 4 + wave) * 8;                                                  \
            __builtin_amdgcn_global_load_lds(                                              \
                Asrc + (size_t)(r0 + (lane >> 3)) * KP + (h) * 64 + (lane & 7) * 8,        \
                base_ + r0 * 64, 16, 0, 0);                                                \
        }                                                                                  \
        _Pragma("unroll")                                                                  \
        for (int it = 0; it < 4; ++it) {                                                   \
            int r0 = (it * 4 + wave) * 8;                                                  \
            __builtin_amdgcn_global_load_lds(                                              \
                Bsrc + (size_t)(r0 + (lane >> 3)) * KP + (h) * 64 + (lane & 7) * 8,        \
                base_ + 8192 + r0 * 64, 16, 0, 0);                                         \
        }                                                                                  \
    }

    f32x4 acc[4][4];
    #pragma unroll
    for (int m = 0; m < 4; ++m)
        #pragma unroll
        for (int n = 0; n < 4; ++n)
            #pragma unroll
            for (int i = 0; i < 4; ++i) acc[m][n][i] = 0.0f;

    STAGE(0, 0);
    #pragma unroll
    for (int h = 0; h < 4; ++h) {
        const int cur = h & 1;
        if (h < 3) {
            STAGE(h + 1, cur ^ 1);
            asm volatile("s_waitcnt vmcnt(8)" ::: "memory");
        } else {
            asm volatile("s_waitcnt vmcnt(0)" ::: "memory");
        }
        __builtin_amdgcn_s_barrier();
        __builtin_amdgcn_sched_barrier(0);
        const short* bA = lds + cur * 16384;
        const short* bB = bA + 8192;
        #pragma unroll
        for (int ksl = 0; ksl < 2; ++ksl) {
            const int csw = ((ksl*4 + q) ^ hs) * 8;
            s16x8 af[4], bf[4];
            #pragma unroll
            for (int m = 0; m < 4; ++m)
                af[m] = *(const s16x8*)(bA + (wm + m*16 + r16) * 64 + csw);
            #pragma unroll
            for (int n = 0; n < 4; ++n)
                bf[n] = *(const s16x8*)(bB + (wn + n*16 + r16) * 64 + csw);
            #pragma unroll
            for (int m = 0; m < 4; ++m)
                #pragma unroll
                for (int n = 0; n < 4; ++n)
                    acc[m][n] = __builtin_amdgcn_mfma_f32_16x16x32_bf16(af[m], bf[n], acc[m][n], 0, 0, 0);
        }
        __builtin_amdgcn_s_barrier();
        __builtin_amdgcn_sched_barrier(0);
    }
#undef STAGE

    // ---- epilogue: transpose via LDS, then 512B-contiguous row stores ----
    float* eld = (float*)lds;
    #pragma unroll
    for (int m = 0; m < 4; ++m) {
        #pragma unroll
        for (int n = 0; n < 4; ++n) {
            #pragma unroll
            for (int i = 0; i < 4; ++i) {
                int row = wm + m*16 + q*4 + i;
                int col = wn + n*16 + r16;
                eld[row * 128 + (col ^ ((row & 7) << 2))] = acc[m][n][i];
            }
        }
    }
    __syncthreads();
    {
        const int c32 = t & 31;                 // lane's 4-float slot within the row
        const int col = c32 * 4;
        const int rsub = (t >> 5) & 1;          // which of the wave's 2 rows
        #pragma unroll
        for (int it = 0; it < 16; ++it) {
            int row = it * 8 + wave * 2 + rsub; // 0..127 (batch-local)
            int bg = bt * 128 + row;
            int rg = nt * 128 + col;
            f32x4 v = *(const f32x4*)&eld[row * 128 + (col ^ ((row & 7) << 2))];
            if (bg < B) {
                float* dst = vout + (size_t)bg * NR + rg;
                if (rg + 3 < NR) {
                    float4 tv = *(const float4*)(vt + rg);
                    v[0] += tv.x; v[1] += tv.y; v[2] += tv.z; v[3] += tv.w;
                    *(f4u*)dst = v;
                } else {
                    #pragma unroll
                    for (int e = 0; e < 4; ++e)
                        if (rg + e < NR) dst[e] = v[e] + vt[rg + e];
                }
            }
        }
    }
}

// ============ K7: kinematic chain -> G_corr (B,24,12) ============
__global__ __launch_bounds__(32) void k_chain(const float* __restrict__ Rg,
        const float* __restrict__ Jg, float* __restrict__ Gc, int B) {
    __shared__ float Gs[32 * 289];
    int b = blockIdx.x * 32 + threadIdx.x;
    if (b >= B) return;
    float* G = &Gs[threadIdx.x * 289];
    float Jl[72];
    const float* Jb = Jg + (size_t)b * 72;
    #pragma unroll
    for (int i = 0; i < 72; ++i) Jl[i] = Jb[i];
    const float* Rb = Rg + (size_t)b * 216;
    G[0]=Rb[0]; G[1]=Rb[1]; G[2]=Rb[2];  G[3]=Jl[0];
    G[4]=Rb[3]; G[5]=Rb[4]; G[6]=Rb[5];  G[7]=Jl[1];
    G[8]=Rb[6]; G[9]=Rb[7]; G[10]=Rb[8]; G[11]=Jl[2];
    #pragma unroll
    for (int i = 1; i < NJ; ++i) {
        const int p = PAR[i];
        const float* Ri = Rb + i*9;
        float r00=Ri[0],r01=Ri[1],r02=Ri[2];
        float r10=Ri[3],r11=Ri[4],r12=Ri[5];
        float r20=Ri[6],r21=Ri[7],r22=Ri[8];
        float px=Jl[p*3+0], py=Jl[p*3+1], pz=Jl[p*3+2];
        float tx = Jl[i*3+0] - (r00*px + r01*py + r02*pz);
        float ty = Jl[i*3+1] - (r10*px + r11*py + r12*pz);
        float tz = Jl[i*3+2] - (r20*px + r21*py + r22*pz);
        const float* gp = &G[p*12];
        float* gi = &G[i*12];
        #pragma unroll
        for (int rr = 0; rr < 3; ++rr) {
            float a0=gp[rr*4+0], a1=gp[rr*4+1], a2=gp[rr*4+2], a3=gp[rr*4+3];
            gi[rr*4+0] = a0*r00 + a1*r10 + a2*r20;
            gi[rr*4+1] = a0*r01 + a1*r11 + a2*r21;
            gi[rr*4+2] = a0*r02 + a1*r12 + a2*r22;
            gi[rr*4+3] = a0*tx + a1*ty + a2*tz + a3;
        }
    }
    float* out = Gc + (size_t)b * 288;
    #pragma unroll
    for (int i = 0; i < NJ; ++i) {
        const float* gi = &G[i*12];
        float jx=Jl[i*3+0], jy=Jl[i*3+1], jz=Jl[i*3+2];
        #pragma unroll
        for (int rr = 0; rr < 3; ++rr) {
            out[i*12+rr*4+0] = gi[rr*4+0];
            out[i*12+rr*4+1] = gi[rr*4+1];
            out[i*12+rr*4+2] = gi[rr*4+2];
            out[i*12+rr*4+3] = gi[rr*4+3] - (gi[rr*4+0]*jx + gi[rr*4+1]*jy + gi[rr*4+2]*jz);
        }
    }
}

// ============ K8: MFMA skinning ============
__global__ __launch_bounds__(256) void k_skin(float* __restrict__ vio,
        const float* __restrict__ W, const float* __restrict__ Gc, int B) {
    __shared__ short Gm[16 * 40];      // [comp][joint], stride 40, zero-padded
    const int t = threadIdx.x;
    const int wave = t >> 6, lane = t & 63;
    const int q = lane >> 4, c = lane & 15;
    const int vb = blockIdx.x * 256 + wave * 64;
    const int b0 = blockIdx.y * 8;

    if (t < 320) ((int*)Gm)[t] = 0;

    s16x8 wf[4];
    #pragma unroll
    for (int m = 0; m < 4; ++m) {
        int vert = vb + m*16 + c;
        if (q < 3 && vert < NV) {
            const float* wp = W + (size_t)vert * NJ + q*8;
            float4 f0 = *(const float4*)(wp);
            float4 f1 = *(const float4*)(wp + 4);
            wf[m][0]=f2bf(f0.x); wf[m][1]=f2bf(f0.y); wf[m][2]=f2bf(f0.z); wf[m][3]=f2bf(f0.w);
            wf[m][4]=f2bf(f1.x); wf[m][5]=f2bf(f1.y); wf[m][6]=f2bf(f1.z); wf[m][7]=f2bf(f1.w);
        } else {
            #pragma unroll
            for (int e = 0; e < 8; ++e) wf[m][e] = 0;
        }
    }
    __syncthreads();

    for (int bb = 0; bb < 8; ++bb) {
        int b = b0 + bb;
        {
            int i0 = t;
            int j0 = i0 / 12, c0 = i0 - j0*12;
            if (i0 < 288) Gm[c0*40 + j0] = f2bf(Gc[(size_t)b*288 + i0]);
            int i1 = t + 256;
            if (i1 < 288) {
                int j1 = i1 / 12, c1 = i1 - j1*12;
                Gm[c1*40 + j1] = f2bf(Gc[(size_t)b*288 + i1]);
            }
        }
        __syncthreads();

        s16x8 af = *(const s16x8*)&Gm[c*40 + q*8];
        #pragma unroll
        for (int m = 0; m < 4; ++m) {
            f32x4 zz = {0.0f, 0.0f, 0.0f, 0.0f};
            f32x4 acc = __builtin_amdgcn_mfma_f32_16x16x32_bf16(af, wf[m], zz, 0, 0, 0);
            int vert = vb + m*16 + c;
            bool ok = (q < 3) && (vert < NV);
            if (ok) {
                float* vp = vio + (size_t)b * NR + (size_t)vert * 3;
                float x = vp[0], y = vp[1], z = vp[2];
                float o = acc[0]*x + acc[1]*y + acc[2]*z + acc[3];
                vp[q] = o;
            }
        }
        __syncthreads();
    }
}

extern "C" void kernel_launch(void* const* d_in, const int* in_sizes, int n_in,
                              void* d_out, int out_size, void* d_ws, size_t ws_size,
                              hipStream_t stream) {
    const float* theta = (const float*)d_in[0];
    const float* beta  = (const float*)d_in[1];
    const float* sd    = (const float*)d_in[2];
    const float* pd    = (const float*)d_in[3];
    const float* Jreg  = (const float*)d_in[4];
    const float* vt    = (const float*)d_in[5];
    const float* W     = (const float*)d_in[6];
    float* out = (float*)d_out;

    const int B = in_sizes[0] / 72;

    float* vregion = out;
    float* Jout    = out + (size_t)B * NR;

    float* Rws   = (float*)d_ws;                          // B*216 f32
    float* Gcws  = Rws + (size_t)B * 216;                 // B*288 f32
    float* pfA   = Gcws + (size_t)B * 288;                // B*224 f32
    short* Atile = (short*)(pfA + (size_t)B * 224);       // (B/128)*128*256 bf16
    short* Btile = Atile + (size_t)(B/128) * 128 * KP;    // 162*128*256 bf16

    float* part = vregion;                                // d_out scratch pre-GEMM (33 MB < 84 MB)
    float* JDt  = vregion + (size_t)NSPLIT * 72 * 224;

    k_rodrigues<<<(B*NJ + 255)/256, 256, 0, stream>>>(theta, beta, Rws, pfA, Atile, B);
    k_convB<<<(NRP*32)/256, 256, 0, stream>>>(pd, sd, Btile);
    k_jdirs<<<NSPLIT, 256, 0, stream>>>(pd, sd, vt, Jreg, part);
    k_jreduce<<<(218*72 + 63)/64, 256, 0, stream>>>(part, JDt);
    k_J<<<B, 128, 0, stream>>>(pfA, JDt, Jout, B);
    k_chain<<<(B + 31)/32, 32, 0, stream>>>(Rws, Jout, Gcws, B);
    {
        dim3 grid(NT, B/128);
        k_gemm<<<grid, 256, 65536, stream>>>(Atile, Btile, vt, vregion, B);
    }
    {
        dim3 grid((NV + 255)/256, (B + 7)/8);
        k_skin<<<grid, 256, 0, stream>>>(vregion, W, Gcws, B);
    }
}

// Round 7
// 155.307 us; speedup vs baseline: 1.3298x; 1.2614x over previous
//
#include <hip/hip_runtime.h>
#include <hip/hip_bf16.h>

#define NJ 24
#define NV 6890
#define NR (NV*3)        // 20670 output rows per batch
#define NPF 207
#define KB 217           // 207 pf + 10 beta
#define KP 256           // padded K (8 x 32)
#define NT 162           // n-tiles (162*128 = 20736 >= NR)
#define NRP (NT*128)
#define NSPLIT 512       // jdirs v-splits
#define VPB 14           // ceil(6890/512)

typedef short s16x8 __attribute__((ext_vector_type(8)));
typedef float f32x4 __attribute__((ext_vector_type(4)));
typedef float f4u   __attribute__((ext_vector_type(4), aligned(4)));

__device__ constexpr int PAR[24] = {-1,0,0,0,1,2,3,4,5,6,7,8,9,9,9,12,13,14,16,17,18,19,20,21};

__device__ __forceinline__ short f2bf(float f) {
    __hip_bfloat16 h = __float2bfloat16(f);
    return *reinterpret_cast<short*>(&h);
}

// ============ K1: Rodrigues -> Rws(f32), pfA(f32), Atiles(bf16, 2-bit chunk swizzle) ============
__global__ __launch_bounds__(256) void k_rodrigues(const float* __restrict__ theta,
        const float* __restrict__ beta, float* __restrict__ Rws,
        float* __restrict__ pfA, short* __restrict__ Atiles, int B) {
    int idx = blockIdx.x * blockDim.x + threadIdx.x;   // b*24 + j
    if (idx >= B * NJ) return;
    int b = idx / NJ, j = idx % NJ;
    float x = theta[b*72 + j*3 + 0];
    float y = theta[b*72 + j*3 + 1];
    float z = theta[b*72 + j*3 + 2];
    float n = sqrtf(x*x + y*y + z*z);
    float a = fmaxf(n, 1e-8f);
    float inv = 1.0f / a;
    float ix = x*inv, iy = y*inv, iz = z*inv;
    float c = cosf(a), s = sinf(a), t = 1.0f - c;
    float r[9];
    r[0] = t*ix*ix + c;     r[1] = t*ix*iy - s*iz;  r[2] = t*ix*iz + s*iy;
    r[3] = t*ix*iy + s*iz;  r[4] = t*iy*iy + c;     r[5] = t*iy*iz - s*ix;
    r[6] = t*ix*iz - s*iy;  r[7] = t*iy*iz + s*ix;  r[8] = t*iz*iz + c;
    float* Rp = Rws + (size_t)idx * 9;
    #pragma unroll
    for (int k = 0; k < 9; ++k) Rp[k] = r[k];

    int rb = b & 127;
    int hs = (rb >> 1) & 3;                            // 2-bit: closed within 32-col windows
    short* At = Atiles + (size_t)(b >> 7) * (128*KP) + (size_t)rb * KP;
    float* pa = pfA + (size_t)b * 224;
    if (j >= 1) {
        #pragma unroll
        for (int kk = 0; kk < 9; ++kk) {
            int k = (j-1)*9 + kk;
            float f = r[kk] - ((kk == 0 || kk == 4 || kk == 8) ? 1.0f : 0.0f);
            At[(((k>>3) ^ hs) << 3) + (k & 7)] = f2bf(f);
            pa[k] = f;
        }
    } else {
        #pragma unroll
        for (int kk = 0; kk < 10; ++kk) {
            int k = NPF + kk;
            float f = beta[b*10 + kk];
            At[(((k>>3) ^ hs) << 3) + (k & 7)] = f2bf(f);
            pa[k] = f;
        }
        for (int k = KB; k < KP; ++k)
            At[(((k>>3) ^ hs) << 3) + (k & 7)] = 0;
    }
}

// ============ K2: build Btiles (bf16, tile-contiguous, 2-bit chunk swizzle) ============
__global__ __launch_bounds__(256) void k_convB(const float* __restrict__ pd,
        const float* __restrict__ sd, short* __restrict__ Btiles) {
    int idx = blockIdx.x * 256 + threadIdx.x;          // (rg, chunk)
    int rg = idx >> 5, c = idx & 31;
    int r = rg & 127, nt = rg >> 7;
    s16x8 v;
    if (rg < NR) {
        int k0 = c * 8;
        if (k0 + 7 < NPF) {
            const float* p = pd + (size_t)rg * NPF + k0;
            #pragma unroll
            for (int k = 0; k < 8; ++k) v[k] = f2bf(p[k]);
        } else {
            #pragma unroll
            for (int k = 0; k < 8; ++k) {
                int col = k0 + k;
                float f = 0.0f;
                if (col < NPF)     f = pd[(size_t)rg * NPF + col];
                else if (col < KB) f = sd[(size_t)rg * 10 + (col - NPF)];
                v[k] = f2bf(f);
            }
        }
    } else {
        #pragma unroll
        for (int k = 0; k < 8; ++k) v[k] = 0;
    }
    int csw = c ^ ((r >> 1) & 3);
    *(s16x8*)&Btiles[(size_t)nt * (128*KP) + (size_t)r * KP + csw * 8] = v;
}

// ============ K3: JD partials, part layout [bi][i(72)][k(224)] ============
__global__ __launch_bounds__(256) void k_jdirs(const float* __restrict__ pd,
        const float* __restrict__ sd, const float* __restrict__ vt,
        const float* __restrict__ Jreg, float* __restrict__ part) {
    __shared__ float wjs[24][VPB];
    int bi = blockIdx.x;
    int v0 = bi * VPB;
    int nv = NV - v0; if (nv > VPB) nv = VPB; if (nv < 0) nv = 0;
    for (int i = threadIdx.x; i < 24*VPB; i += 256) {
        int j = i / VPB, vv = i - j*VPB;
        wjs[j][vv] = (vv < nv) ? Jreg[(size_t)j * NV + v0 + vv] : 0.0f;
    }
    __syncthreads();
    int k = threadIdx.x;
    float acc[72];
    #pragma unroll
    for (int i = 0; i < 72; ++i) acc[i] = 0.0f;
    for (int vv = 0; vv < VPB; ++vv) {
        int v = v0 + vv;
        if (v >= NV) break;
        #pragma unroll
        for (int c = 0; c < 3; ++c) {
            int row = v*3 + c;
            float val = 0.0f;
            if (k < NPF)      val = pd[(size_t)row * NPF + k];
            else if (k < KB)  val = sd[(size_t)row * 10 + (k - NPF)];
            else if (k == KB) val = vt[row];
            #pragma unroll
            for (int j = 0; j < 24; ++j) acc[j*3 + c] += wjs[j][vv] * val;
        }
    }
    if (k < 224) {
        float* p = part + (size_t)bi * (72*224);
        #pragma unroll
        for (int i = 0; i < 72; ++i) p[i*224 + k] = acc[i];
    }
}

// ============ K4a: reduce 512 -> 8 partials, coalesced (lanes walk k) ============
__global__ __launch_bounds__(256) void k_jreduce1(const float* __restrict__ part,
        float* __restrict__ part2) {
    int i = blockIdx.x;            // 0..71
    int s = blockIdx.y;            // 0..7
    int k = threadIdx.x;
    if (k >= 224) return;
    float acc = 0.0f;
    #pragma unroll 4
    for (int bi = s*64; bi < s*64 + 64; ++bi)
        acc += part[(size_t)bi * (72*224) + i*224 + k];
    part2[((size_t)s * 72 + i) * 224 + k] = acc;
}

// ============ K4b: reduce 8 -> JDt[k][72], coalesced ============
__global__ __launch_bounds__(256) void k_jreduce2(const float* __restrict__ part2,
        float* __restrict__ JDt) {
    int e = blockIdx.x * 256 + threadIdx.x;    // e = i*224 + k
    if (e >= 72*224) return;
    int i = e / 224, k = e - i*224;
    float s = 0.0f;
    #pragma unroll
    for (int ss = 0; ss < 8; ++ss)
        s += part2[((size_t)ss * 72 + i) * 224 + k];
    if (k < 218) JDt[k*72 + i] = s;
}

// ============ K5: J[b][jc] = JDt[217][jc] + sum_k pfA[b][k]*JDt[k][jc] ============
__global__ __launch_bounds__(128) void k_J(const float* __restrict__ pfA,
        const float* __restrict__ JDt, float* __restrict__ Jout, int B) {
    int b = blockIdx.x, t = threadIdx.x;
    if (t >= 72) return;
    const float* pa = pfA + (size_t)b * 224;
    float acc = JDt[217*72 + t];
    #pragma unroll 7
    for (int k = 0; k < KB; ++k) acc += pa[k] * JDt[k*72 + t];
    Jout[(size_t)b * 72 + t] = acc;
}

// ============ K6: MFMA GEMM, BK=32, 8 phases, 32 KB LDS (5 blocks/CU) ============
__global__ __launch_bounds__(256) void k_gemm(const short* __restrict__ At,
        const short* __restrict__ Bt, const float* __restrict__ vt,
        float* __restrict__ vout, int B) {
    extern __shared__ short lds[];                 // 2 bufs x (A 4096 + B 4096) shorts = 32 KB
    const int t = threadIdx.x;
    const int nt = blockIdx.x, bt = blockIdx.y;
    const int wave = t >> 6, lane = t & 63;
    const short* Asrc = At + (size_t)bt * (128*KP);
    const short* Bsrc = Bt + (size_t)nt * (128*KP);

    const int wm = (wave >> 1) * 64, wn = (wave & 1) * 64;
    const int q = lane >> 4, r16 = lane & 15;
    const int hs2 = (r16 >> 1) & 3;

    // per chunk: 2 A + 2 B gload_lds per thread; wave-instr = 16 rows x 32 shorts = 1 KB
#define STAGE(h, s)                                                                        \
    {                                                                                      \
        short* base_ = lds + (s) * 8192;                                                   \
        _Pragma("unroll")                                                                  \
        for (int it = 0; it < 2; ++it) {                                                   \
            int r0 = (it * 4 + wave) * 16;                                                 \
            __builtin_amdgcn_global_load_lds(                                              \
                Asrc + (size_t)(r0 + (lane >> 2)) * KP + (h) * 32 + (lane & 3) * 8,        \
                base_ + r0 * 32, 16, 0, 0);                                                \
        }                                                                                  \
        _Pragma("unroll")                                                                  \
        for (int it = 0; it < 2; ++it) {                                                   \
            int r0 = (it * 4 + wave) * 16;                                                 \
            __builtin_amdgcn_global_load_lds(                                              \
                Bsrc + (size_t)(r0 + (lane >> 2)) * KP + (h) * 32 + (lane & 3) * 8,        \
                base_ + 4096 + r0 * 32, 16, 0, 0);                                         \
        }                                                                                  \
    }

    f32x4 acc[4][4];
    #pragma unroll
    for (int m = 0; m < 4; ++m)
        #pragma unroll
        for (int n = 0; n < 4; ++n)
            #pragma unroll
            for (int i = 0; i < 4; ++i) acc[m][n][i] = 0.0f;

    STAGE(0, 0);
    #pragma unroll
    for (int h = 0; h < 8; ++h) {
        const int cur = h & 1;
        if (h < 7) {
            STAGE(h + 1, cur ^ 1);
            asm volatile("s_waitcnt vmcnt(4)" ::: "memory");
        } else {
            asm volatile("s_waitcnt vmcnt(0)" ::: "memory");
        }
        __builtin_amdgcn_s_barrier();
        __builtin_amdgcn_sched_barrier(0);
        const short* bA = lds + cur * 8192;
        const short* bB = bA + 4096;
        const int csw = (q ^ hs2) * 8;
        s16x8 af[4], bf[4];
        #pragma unroll
        for (int m = 0; m < 4; ++m)
            af[m] = *(const s16x8*)(bA + (wm + m*16 + r16) * 32 + csw);
        #pragma unroll
        for (int n = 0; n < 4; ++n)
            bf[n] = *(const s16x8*)(bB + (wn + n*16 + r16) * 32 + csw);
        #pragma unroll
        for (int m = 0; m < 4; ++m)
            #pragma unroll
            for (int n = 0; n < 4; ++n)
                acc[m][n] = __builtin_amdgcn_mfma_f32_16x16x32_bf16(af[m], bf[n], acc[m][n], 0, 0, 0);
        __builtin_amdgcn_s_barrier();
        __builtin_amdgcn_sched_barrier(0);
    }
#undef STAGE

    // ---- epilogue: two 64-row halves through 32 KB LDS, 512B-contiguous row stores ----
    float* eld = (float*)lds;
    #pragma unroll
    for (int half = 0; half < 2; ++half) {
        if ((wave >> 1) == half) {
            #pragma unroll
            for (int m = 0; m < 4; ++m) {
                #pragma unroll
                for (int n = 0; n < 4; ++n) {
                    #pragma unroll
                    for (int i = 0; i < 4; ++i) {
                        int row_l = m*16 + q*4 + i;              // 0..63
                        int col = wn + n*16 + r16;               // 0..127
                        eld[row_l * 128 + (col ^ ((row_l & 7) << 2))] = acc[m][n][i];
                    }
                }
            }
        }
        __syncthreads();
        {
            const int c32 = t & 31;
            const int col = c32 * 4;
            const int rsub = (t >> 5) & 1;
            #pragma unroll
            for (int it = 0; it < 8; ++it) {
                int row_l = it * 8 + wave * 2 + rsub;            // 0..63
                int bg = bt * 128 + half * 64 + row_l;
                int rg = nt * 128 + col;
                f32x4 v = *(const f32x4*)&eld[row_l * 128 + (col ^ ((row_l & 7) << 2))];
                if (bg < B) {
                    float* dst = vout + (size_t)bg * NR + rg;
                    if (rg + 3 < NR) {
                        float4 tv = *(const float4*)(vt + rg);
                        v[0] += tv.x; v[1] += tv.y; v[2] += tv.z; v[3] += tv.w;
                        *(f4u*)dst = v;
                    } else {
                        #pragma unroll
                        for (int e = 0; e < 4; ++e)
                            if (rg + e < NR) dst[e] = v[e] + vt[rg + e];
                    }
                }
            }
        }
        __syncthreads();
    }
}

// ============ K7: kinematic chain -> G_corr (B,24,12) ============
__global__ __launch_bounds__(32) void k_chain(const float* __restrict__ Rg,
        const float* __restrict__ Jg, float* __restrict__ Gc, int B) {
    __shared__ float Gs[32 * 289];
    int b = blockIdx.x * 32 + threadIdx.x;
    if (b >= B) return;
    float* G = &Gs[threadIdx.x * 289];
    float Jl[72];
    const float* Jb = Jg + (size_t)b * 72;
    #pragma unroll
    for (int i = 0; i < 72; ++i) Jl[i] = Jb[i];
    const float* Rb = Rg + (size_t)b * 216;
    G[0]=Rb[0]; G[1]=Rb[1]; G[2]=Rb[2];  G[3]=Jl[0];
    G[4]=Rb[3]; G[5]=Rb[4]; G[6]=Rb[5];  G[7]=Jl[1];
    G[8]=Rb[6]; G[9]=Rb[7]; G[10]=Rb[8]; G[11]=Jl[2];
    #pragma unroll
    for (int i = 1; i < NJ; ++i) {
        const int p = PAR[i];
        const float* Ri = Rb + i*9;
        float r00=Ri[0],r01=Ri[1],r02=Ri[2];
        float r10=Ri[3],r11=Ri[4],r12=Ri[5];
        float r20=Ri[6],r21=Ri[7],r22=Ri[8];
        float px=Jl[p*3+0], py=Jl[p*3+1], pz=Jl[p*3+2];
        float tx = Jl[i*3+0] - (r00*px + r01*py + r02*pz);
        float ty = Jl[i*3+1] - (r10*px + r11*py + r12*pz);
        float tz = Jl[i*3+2] - (r20*px + r21*py + r22*pz);
        const float* gp = &G[p*12];
        float* gi = &G[i*12];
        #pragma unroll
        for (int rr = 0; rr < 3; ++rr) {
            float a0=gp[rr*4+0], a1=gp[rr*4+1], a2=gp[rr*4+2], a3=gp[rr*4+3];
            gi[rr*4+0] = a0*r00 + a1*r10 + a2*r20;
            gi[rr*4+1] = a0*r01 + a1*r11 + a2*r21;
            gi[rr*4+2] = a0*r02 + a1*r12 + a2*r22;
            gi[rr*4+3] = a0*tx + a1*ty + a2*tz + a3;
        }
    }
    float* out = Gc + (size_t)b * 288;
    #pragma unroll
    for (int i = 0; i < NJ; ++i) {
        const float* gi = &G[i*12];
        float jx=Jl[i*3+0], jy=Jl[i*3+1], jz=Jl[i*3+2];
        #pragma unroll
        for (int rr = 0; rr < 3; ++rr) {
            out[i*12+rr*4+0] = gi[rr*4+0];
            out[i*12+rr*4+1] = gi[rr*4+1];
            out[i*12+rr*4+2] = gi[rr*4+2];
            out[i*12+rr*4+3] = gi[rr*4+3] - (gi[rr*4+0]*jx + gi[rr*4+1]*jy + gi[rr*4+2]*jz);
        }
    }
}

// ============ K8: MFMA skinning ============
__global__ __launch_bounds__(256) void k_skin(float* __restrict__ vio,
        const float* __restrict__ W, const float* __restrict__ Gc, int B) {
    __shared__ short Gm[16 * 40];
    const int t = threadIdx.x;
    const int wave = t >> 6, lane = t & 63;
    const int q = lane >> 4, c = lane & 15;
    const int vb = blockIdx.x * 256 + wave * 64;
    const int b0 = blockIdx.y * 8;

    if (t < 320) ((int*)Gm)[t] = 0;

    s16x8 wf[4];
    #pragma unroll
    for (int m = 0; m < 4; ++m) {
        int vert = vb + m*16 + c;
        if (q < 3 && vert < NV) {
            const float* wp = W + (size_t)vert * NJ + q*8;
            float4 f0 = *(const float4*)(wp);
            float4 f1 = *(const float4*)(wp + 4);
            wf[m][0]=f2bf(f0.x); wf[m][1]=f2bf(f0.y); wf[m][2]=f2bf(f0.z); wf[m][3]=f2bf(f0.w);
            wf[m][4]=f2bf(f1.x); wf[m][5]=f2bf(f1.y); wf[m][6]=f2bf(f1.z); wf[m][7]=f2bf(f1.w);
        } else {
            #pragma unroll
            for (int e = 0; e < 8; ++e) wf[m][e] = 0;
        }
    }
    __syncthreads();

    for (int bb = 0; bb < 8; ++bb) {
        int b = b0 + bb;
        {
            int i0 = t;
            int j0 = i0 / 12, c0 = i0 - j0*12;
            if (i0 < 288) Gm[c0*40 + j0] = f2bf(Gc[(size_t)b*288 + i0]);
            int i1 = t + 256;
            if (i1 < 288) {
                int j1 = i1 / 12, c1 = i1 - j1*12;
                Gm[c1*40 + j1] = f2bf(Gc[(size_t)b*288 + i1]);
            }
        }
        __syncthreads();

        s16x8 af = *(const s16x8*)&Gm[c*40 + q*8];
        #pragma unroll
        for (int m = 0; m < 4; ++m) {
            f32x4 zz = {0.0f, 0.0f, 0.0f, 0.0f};
            f32x4 acc = __builtin_amdgcn_mfma_f32_16x16x32_bf16(af, wf[m], zz, 0, 0, 0);
            int vert = vb + m*16 + c;
            bool ok = (q < 3) && (vert < NV);
            if (ok) {
                float* vp = vio + (size_t)b * NR + (size_t)vert * 3;
                float x = vp[0], y = vp[1], z = vp[2];
                float o = acc[0]*x + acc[1]*y + acc[2]*z + acc[3];
                vp[q] = o;
            }
        }
        __syncthreads();
    }
}

extern "C" void kernel_launch(void* const* d_in, const int* in_sizes, int n_in,
                              void* d_out, int out_size, void* d_ws, size_t ws_size,
                              hipStream_t stream) {
    const float* theta = (const float*)d_in[0];
    const float* beta  = (const float*)d_in[1];
    const float* sd    = (const float*)d_in[2];
    const float* pd    = (const float*)d_in[3];
    const float* Jreg  = (const float*)d_in[4];
    const float* vt    = (const float*)d_in[5];
    const float* W     = (const float*)d_in[6];
    float* out = (float*)d_out;

    const int B = in_sizes[0] / 72;

    float* vregion = out;
    float* Jout    = out + (size_t)B * NR;

    float* Rws   = (float*)d_ws;                          // B*216 f32
    float* Gcws  = Rws + (size_t)B * 216;                 // B*288 f32
    float* pfA   = Gcws + (size_t)B * 288;                // B*224 f32
    short* Atile = (short*)(pfA + (size_t)B * 224);       // (B/128)*128*256 bf16
    short* Btile = Atile + (size_t)(B/128) * 128 * KP;    // 162*128*256 bf16

    float* part  = vregion;                               // d_out scratch pre-GEMM (~33.6 MB < 84 MB)
    float* part2 = vregion + (size_t)NSPLIT * 72 * 224;   // 8*72*224
    float* JDt   = part2 + (size_t)8 * 72 * 224;          // 218*72

    k_rodrigues<<<(B*NJ + 255)/256, 256, 0, stream>>>(theta, beta, Rws, pfA, Atile, B);
    k_convB<<<(NRP*32)/256, 256, 0, stream>>>(pd, sd, Btile);
    k_jdirs<<<NSPLIT, 256, 0, stream>>>(pd, sd, vt, Jreg, part);
    {
        dim3 grid(72, 8);
        k_jreduce1<<<grid, 256, 0, stream>>>(part, part2);
    }
    k_jreduce2<<<(72*224 + 255)/256, 256, 0, stream>>>(part2, JDt);
    k_J<<<B, 128, 0, stream>>>(pfA, JDt, Jout, B);
    k_chain<<<(B + 31)/32, 32, 0, stream>>>(Rws, Jout, Gcws, B);
    {
        dim3 grid(NT, B/128);
        k_gemm<<<grid, 256, 32768, stream>>>(Atile, Btile, vt, vregion, B);
    }
    {
        dim3 grid((NV + 255)/256, (B + 7)/8);
        k_skin<<<grid, 256, 0, stream>>>(vregion, W, Gcws, B);
    }
}